// Round 3
// baseline (371.972 us; speedup 1.0000x reference)
//
#include <hip/hip_runtime.h>

#define D_MODEL 1024
#define D_FFN   4096
#define SEQ     2048
#define NROWS   4096   // B*S
#define QKV_LD  3072

typedef __bf16 bf16x8 __attribute__((ext_vector_type(8)));
typedef float  floatx4 __attribute__((ext_vector_type(4)));

#define MFMA_BF16 __builtin_amdgcn_mfma_f32_16x16x32_bf16

__device__ __forceinline__ unsigned short f2bf(float f) {
  unsigned int u = __float_as_uint(f);
  u += 0x7FFFu + ((u >> 16) & 1u);   // RNE
  return (unsigned short)(u >> 16);
}

// DPP row_ror<N> within 16-lane rows (VALU-speed cross-lane; no LDS pipe)
template <int C>
__device__ __forceinline__ float ror16(float x) {
  return __int_as_float(
      __builtin_amdgcn_mov_dpp(__float_as_int(x), 0x120 | C, 0xf, 0xf, true));
}

// async global->LDS, 16B per lane. LDS dest = wave-uniform base + lane*16.
__device__ __forceinline__ void async16(const unsigned short* g, unsigned short* l) {
  __builtin_amdgcn_global_load_lds(
      (const __attribute__((address_space(1))) unsigned int*)g,
      (__attribute__((address_space(3))) unsigned int*)l, 16, 0, 0);
}

// ---------------- fp32 -> bf16 elementwise ----------------
__global__ __launch_bounds__(256) void k_f32_to_bf16(
    const float* __restrict__ in, unsigned short* __restrict__ outp, long n) {
  long i = ((long)blockIdx.x * 256 + threadIdx.x) * 4;
  if (i >= n) return;
  float4 v = *(const float4*)(in + i);
  ushort4 o;
  o.x = f2bf(v.x); o.y = f2bf(v.y); o.z = f2bf(v.z); o.w = f2bf(v.w);
  *(ushort4*)(outp + i) = o;
}

// ------------- transpose+convert: W[R][C] f32 -> WT[C][R] bf16 -------------
__global__ __launch_bounds__(256) void k_transpose_bf16(
    const float* __restrict__ W, unsigned short* __restrict__ WT, int R, int C) {
  __shared__ float tile[32][33];
  int tx = threadIdx.x & 31, ty = threadIdx.x >> 5;
  long bx = (long)blockIdx.x * 32;
  long by = (long)blockIdx.y * 32;
  #pragma unroll
  for (int j = 0; j < 4; j++)
    tile[ty + j * 8][tx] = W[(by + ty + j * 8) * C + bx + tx];
  __syncthreads();
  #pragma unroll
  for (int j = 0; j < 4; j++)
    WT[(bx + ty + j * 8) * R + by + tx] = f2bf(tile[tx][ty + j * 8]);
}

// ------------- 1024x1024 weight transposes fused (z: Wq,Wk,Wv -> WqkvT; Wo -> WoT) ------
__global__ __launch_bounds__(256) void k_transpose_sq(
    const float* __restrict__ Wq, const float* __restrict__ Wk,
    const float* __restrict__ Wv, const float* __restrict__ Wo,
    unsigned short* __restrict__ WqkvT, unsigned short* __restrict__ WoT) {
  __shared__ float tile[32][33];
  int z = blockIdx.z;
  const float* W = (z == 0) ? Wq : (z == 1) ? Wk : (z == 2) ? Wv : Wo;
  unsigned short* dst = (z < 3) ? (WqkvT + (size_t)z * D_MODEL * D_MODEL) : WoT;
  int tx = threadIdx.x & 31, ty = threadIdx.x >> 5;
  long bx = (long)blockIdx.x * 32;
  long by = (long)blockIdx.y * 32;
  #pragma unroll
  for (int j = 0; j < 4; j++)
    tile[ty + j * 8][tx] = W[(by + ty + j * 8) * D_MODEL + bx + tx];
  __syncthreads();
  #pragma unroll
  for (int j = 0; j < 4; j++)
    dst[(bx + ty + j * 8) * D_MODEL + by + tx] = f2bf(tile[tx][ty + j * 8]);
}

__global__ __launch_bounds__(256) void k_pack_bias(
    const float* __restrict__ bq, const float* __restrict__ bk,
    const float* __restrict__ bv, float* __restrict__ dst) {
  int i = blockIdx.x * 256 + threadIdx.x;
  if (i >= 3072) return;
  float v = (i < 1024) ? bq[i] : (i < 2048) ? bk[i - 1024] : bv[i - 2048];
  dst[i] = v;
}

// ------------- V^T: QKV[:, 2048+d] -> Vt[d][row]  (bf16) -------------
__global__ __launch_bounds__(256) void k_transpose_v(
    const unsigned short* __restrict__ QKV, unsigned short* __restrict__ Vt) {
  __shared__ unsigned short tile[64][72];
  int r0 = blockIdx.x * 64;
  int c0 = blockIdx.y * 64;
  int tx = threadIdx.x & 15, ty = threadIdx.x >> 4;
  #pragma unroll
  for (int j = 0; j < 4; j++) {
    int r = ty + j * 16;
    *(ushort4*)&tile[r][tx * 4] =
        *(const ushort4*)(QKV + (long)(r0 + r) * QKV_LD + 2048 + c0 + tx * 4);
  }
  __syncthreads();
  #pragma unroll
  for (int j = 0; j < 4; j++) {
    int d = ty + j * 16;
    ushort4 o;
    o.x = tile[tx * 4 + 0][d];
    o.y = tile[tx * 4 + 1][d];
    o.z = tile[tx * 4 + 2][d];
    o.w = tile[tx * 4 + 3][d];
    *(ushort4*)(Vt + (long)(c0 + d) * NROWS + r0 + tx * 4) = o;
  }
}

// ============ 128x128 8-wave bf16 MFMA GEMM, 2 blocks/CU, counted vmcnt ============
// C[M][N] = A[M][K] @ Bt[N][K]^T + bias. BK=64, double-buffered 64 KiB static LDS.
__global__ __launch_bounds__(512, 4) void k_gemm128(
    const unsigned short* __restrict__ A,
    const unsigned short* __restrict__ Bt,
    const float* __restrict__ bias,
    void* __restrict__ Cp, int M, int N, int K, int flags) {
  __shared__ unsigned short lds[2 * 16384];   // [2 buf][A 8192 | B 8192] u16 = 64 KiB
  int tid = threadIdx.x, lane = tid & 63, wave = tid >> 6;
  int quad = lane >> 4, l16 = lane & 15;
  int wm = wave >> 2, wn = wave & 3;          // 2M x 4N wave grid

  int gx = gridDim.x;
  int nwg = gx * gridDim.y;                   // % 8 == 0
  int orig = blockIdx.y * gx + blockIdx.x;
  int wg = (orig & 7) * (nwg >> 3) + (orig >> 3);
  long bm = (long)(wg % gx) * 128;
  long bn = (long)(wg / gx) * 128;

  int T = K / 64;

  const floatx4 fz = {0.f, 0.f, 0.f, 0.f};
  floatx4 acc[4][2];
  #pragma unroll
  for (int i = 0; i < 4; i++)
    #pragma unroll
    for (int j = 0; j < 2; j++) acc[i][j] = fz;

  int srow = tid >> 3;
  int sc = (tid & 7) ^ (srow & 7);
  const unsigned short* Ag = A + (bm + srow) * (long)K + sc * 8;
  const unsigned short* Bg = Bt + (bn + srow) * (long)K + sc * 8;

  auto stage = [&](int tt, int c) {
    unsigned short* An = lds + c * 16384;
    unsigned short* Bn = An + 8192;
    long ko = (long)tt * 64;
    async16(Ag + ko, An + wave * 512);
    async16(Ag + 64 * (long)K + ko, An + 4096 + wave * 512);
    async16(Bg + ko, Bn + wave * 512);
    async16(Bg + 64 * (long)K + ko, Bn + 4096 + wave * 512);
  };

  int aoff = (wm * 64 + l16) * 64;
  int boff = (wn * 32 + l16) * 64;
  int sw = l16 & 7;
  int ca0 = (quad ^ sw) * 8;          // k-chunks 0..3 (h=0)
  int ca1 = ((4 + quad) ^ sw) * 8;    // k-chunks 4..7 (h=1)

  stage(0, 0);
  for (int t = 0; t < T; t++) {
    int c = t & 1;
    const unsigned short* Ac = lds + c * 16384;
    const unsigned short* Bc = Ac + 8192;
    int tn = (t + 1 < T) ? t + 1 : T - 1;   // clamp keeps vmcnt count uniform
    stage(tn, c ^ 1);
    __asm__ volatile("s_waitcnt vmcnt(4)" ::: "memory");
    __builtin_amdgcn_s_barrier();

    bf16x8 af[4][2], bfr[2][2];
    #pragma unroll
    for (int m = 0; m < 4; m++) {
      af[m][0] = *(const bf16x8*)(Ac + aoff + m * 1024 + ca0);
      af[m][1] = *(const bf16x8*)(Ac + aoff + m * 1024 + ca1);
    }
    #pragma unroll
    for (int n = 0; n < 2; n++) {
      bfr[n][0] = *(const bf16x8*)(Bc + boff + n * 1024 + ca0);
      bfr[n][1] = *(const bf16x8*)(Bc + boff + n * 1024 + ca1);
    }
    __asm__ volatile("s_waitcnt lgkmcnt(0)" ::: "memory");
    __builtin_amdgcn_s_setprio(1);
    #pragma unroll
    for (int h = 0; h < 2; h++)
      #pragma unroll
      for (int m = 0; m < 4; m++)
        #pragma unroll
        for (int n = 0; n < 2; n++)
          acc[m][n] = MFMA_BF16(af[m][h], bfr[n][h], acc[m][n], 0, 0, 0);
    __builtin_amdgcn_s_setprio(0);
    __builtin_amdgcn_s_barrier();
  }

  bool f32out = (flags & 1) != 0;
  bool relu   = (flags & 2) != 0;
  float* outf = (float*)Cp;
  unsigned short* outh = (unsigned short*)Cp;
  #pragma unroll
  for (int n = 0; n < 2; n++) {
    long col = bn + wn * 32 + n * 16 + l16;
    float bvv = bias[col];
    #pragma unroll
    for (int m = 0; m < 4; m++) {
      long row = bm + wm * 64 + m * 16 + quad * 4;
      #pragma unroll
      for (int r = 0; r < 4; r++) {
        float v = acc[m][n][r] + bvv;
        if (relu) v = fmaxf(v, 0.0f);
        if (f32out) outf[(row + r) * (long)N + col] = v;
        else        outh[(row + r) * (long)N + col] = f2bf(v);
      }
    }
  }
}

// ============ 256x256 8-wave 8-phase bf16 MFMA GEMM (T2+T3+T4+T5) ============
// Used for the up-projection (M=4096, N=4096, K=1024): grid 16x16 = 256 blocks.
__global__ __launch_bounds__(512, 2) void k_gemm256(
    const unsigned short* __restrict__ A,
    const unsigned short* __restrict__ Bt,
    const float* __restrict__ bias,
    void* __restrict__ Cp, int M, int N, int K, int flags) {
  extern __shared__ unsigned short lds[];   // [2 buf][A|B][256*64] u16 = 128 KiB
  int tid = threadIdx.x, lane = tid & 63, wave = tid >> 6;
  int quad = lane >> 4, l16 = lane & 15;
  int wm = wave >> 2, wn = wave & 3;        // 2M x 4N wave grid

  int nwg = gridDim.x * gridDim.y;
  int orig = blockIdx.y * gridDim.x + blockIdx.x;
  int wg = (orig & 7) * (nwg >> 3) + (orig >> 3);
  long bm = (long)(wg & 15) * 256;          // gridDim.x == 16 always
  long bn = (long)(wg >> 4) * 256;

  int z = blockIdx.z;
  int Ks = K / gridDim.z;
  long zb = (long)z * Ks;
  int T = Ks / 64;

  const floatx4 fz = {0.f, 0.f, 0.f, 0.f};
  floatx4 acc[8][4];
  #pragma unroll
  for (int i = 0; i < 8; i++)
    #pragma unroll
    for (int j = 0; j < 4; j++) acc[i][j] = fz;

  int srow = tid >> 3;
  int sc = (tid & 7) ^ (srow & 7);
  const unsigned short* Ag = A + (bm + srow) * (long)K + zb + sc * 8;
  const unsigned short* Bg = Bt + (bn + srow) * (long)K + zb + sc * 8;

  auto stage = [&](int tt, int c) {
    unsigned short* An = lds + c * 32768;
    unsigned short* Bn = An + 16384;
    long ko = (long)tt * 64;
    #pragma unroll
    for (int i = 0; i < 4; i++) {
      async16(Ag + (long)i * 64 * K + ko, An + i * 4096 + wave * 512);
      async16(Bg + (long)i * 64 * K + ko, Bn + i * 4096 + wave * 512);
    }
  };

  int aoff = (wm * 128 + l16) * 64;
  int boff = (wn * 64 + l16) * 64;
  int sw = l16 & 7;
  int ca0 = (quad ^ sw) * 8;          // k-chunks 0..3 (h=0)
  int ca1 = ((4 + quad) ^ sw) * 8;    // k-chunks 4..7 (h=1)

  stage(0, 0);
  for (int t = 0; t < T; t++) {
    int c = t & 1;
    const unsigned short* Ac = lds + c * 32768;
    const unsigned short* Bc = Ac + 16384;
    int tn = (t + 1 < T) ? t + 1 : T - 1;   // clamp keeps vmcnt count uniform
    stage(tn, c ^ 1);
    __asm__ volatile("s_waitcnt vmcnt(8)" ::: "memory");
    __builtin_amdgcn_s_barrier();

    bf16x8 af[8], b0, b1;
    // ---- phase 0: h0, n{0,1} ----
    #pragma unroll
    for (int m = 0; m < 8; m++) af[m] = *(const bf16x8*)(Ac + aoff + m * 1024 + ca0);
    b0 = *(const bf16x8*)(Bc + boff + 0 * 1024 + ca0);
    b1 = *(const bf16x8*)(Bc + boff + 1 * 1024 + ca0);
    __asm__ volatile("s_waitcnt lgkmcnt(0)" ::: "memory");
    __builtin_amdgcn_s_setprio(1);
    #pragma unroll
    for (int m = 0; m < 8; m++) acc[m][0] = MFMA_BF16(af[m], b0, acc[m][0], 0, 0, 0);
    #pragma unroll
    for (int m = 0; m < 8; m++) acc[m][1] = MFMA_BF16(af[m], b1, acc[m][1], 0, 0, 0);
    __builtin_amdgcn_s_setprio(0);
    __builtin_amdgcn_s_barrier();
    // ---- phase 1: h0, n{2,3} (reuses af) ----
    b0 = *(const bf16x8*)(Bc + boff + 2 * 1024 + ca0);
    b1 = *(const bf16x8*)(Bc + boff + 3 * 1024 + ca0);
    __asm__ volatile("s_waitcnt lgkmcnt(0)" ::: "memory");
    __builtin_amdgcn_s_setprio(1);
    #pragma unroll
    for (int m = 0; m < 8; m++) acc[m][2] = MFMA_BF16(af[m], b0, acc[m][2], 0, 0, 0);
    #pragma unroll
    for (int m = 0; m < 8; m++) acc[m][3] = MFMA_BF16(af[m], b1, acc[m][3], 0, 0, 0);
    __builtin_amdgcn_s_setprio(0);
    __builtin_amdgcn_s_barrier();
    // ---- phase 2: h1, n{0,1} ----
    #pragma unroll
    for (int m = 0; m < 8; m++) af[m] = *(const bf16x8*)(Ac + aoff + m * 1024 + ca1);
    b0 = *(const bf16x8*)(Bc + boff + 0 * 1024 + ca1);
    b1 = *(const bf16x8*)(Bc + boff + 1 * 1024 + ca1);
    __asm__ volatile("s_waitcnt lgkmcnt(0)" ::: "memory");
    __builtin_amdgcn_s_setprio(1);
    #pragma unroll
    for (int m = 0; m < 8; m++) acc[m][0] = MFMA_BF16(af[m], b0, acc[m][0], 0, 0, 0);
    #pragma unroll
    for (int m = 0; m < 8; m++) acc[m][1] = MFMA_BF16(af[m], b1, acc[m][1], 0, 0, 0);
    __builtin_amdgcn_s_setprio(0);
    __builtin_amdgcn_s_barrier();
    // ---- phase 3: h1, n{2,3} ----
    b0 = *(const bf16x8*)(Bc + boff + 2 * 1024 + ca1);
    b1 = *(const bf16x8*)(Bc + boff + 3 * 1024 + ca1);
    __asm__ volatile("s_waitcnt lgkmcnt(0)" ::: "memory");
    __builtin_amdgcn_s_setprio(1);
    #pragma unroll
    for (int m = 0; m < 8; m++) acc[m][2] = MFMA_BF16(af[m], b0, acc[m][2], 0, 0, 0);
    #pragma unroll
    for (int m = 0; m < 8; m++) acc[m][3] = MFMA_BF16(af[m], b1, acc[m][3], 0, 0, 0);
    __builtin_amdgcn_s_setprio(0);
    __builtin_amdgcn_s_barrier();
  }

  bool f32out = (flags & 1) != 0;
  bool relu   = (flags & 2) != 0;
  float* outf = (float*)Cp + (size_t)z * M * (size_t)N;
  unsigned short* outh = (unsigned short*)Cp;
  #pragma unroll
  for (int n = 0; n < 4; n++) {
    long col = bn + wn * 64 + n * 16 + l16;
    float bvv = (z == 0) ? bias[col] : 0.0f;
    #pragma unroll
    for (int m = 0; m < 8; m++) {
      long row = bm + wm * 128 + m * 16 + quad * 4;
      #pragma unroll
      for (int r = 0; r < 4; r++) {
        float v = acc[m][n][r] + bvv;
        if (relu) v = fmaxf(v, 0.0f);
        if (f32out) outf[(row + r) * (long)N + col] = v;
        else        outh[(row + r) * (long)N + col] = f2bf(v);
      }
    }
  }
}

// ---------------- flash attention (causal), LDS-staged K/V ----------------
// One q-tile (64 rows) per block; 1024 blocks, heavy-first (qt descending).
// LDS 25.6 KB -> up to 6 blocks/CU; whole grid co-resident (~16 waves/CU).
// Softmax: max on RAW scores (scale folded once into Mg / exp via fma);
// per-thread defer-max (THR=8) skips alpha rescale when max barely grows.
#define PLD 72
__global__ __launch_bounds__(256) void k_attn(
    const unsigned short* __restrict__ QKV,
    const unsigned short* __restrict__ Vt,
    unsigned short* __restrict__ Omat) {
  __shared__ unsigned short Ks[64 * 64];   // [kv][d], chunk-swizzled
  __shared__ unsigned short Vs[64 * 64];   // [d][kv], chunk-swizzled
  __shared__ unsigned short Ps[4][16 * PLD];
  int tid = threadIdx.x;
  int lane = tid & 63, wave = tid >> 6;
  int quad = lane >> 4, l16 = lane & 15;
  int z = blockIdx.x;
  int bh = z & 31;
  int qt = 31 - (z >> 5);          // heavy blocks dispatch first
  int b = bh >> 4, h = bh & 15;
  long rowbase = (long)b * SEQ;
  int hd0 = h * 64;
  unsigned short* pw = &Ps[wave][0];
  const float SCL = 0.18033688f;   // 0.125 * log2(e)
  const floatx4 fz = {0.f, 0.f, 0.f, 0.f};

  int r_in = lane >> 3;
  int cpos = lane & 7;

  bf16x8 ones;
  #pragma unroll
  for (int i = 0; i < 8; i++) ones[i] = (__bf16)1.0f;

  int q0w = qt * 64 + wave * 16;
  int qrow = q0w + quad * 4;
  int ntiles = qt + 1;

  bf16x8 qf0, qf1;
  {
    const unsigned short* qp_ =
        QKV + (rowbase + q0w + l16) * (long)QKV_LD + hd0 + quad * 8;
    qf0 = *(const bf16x8*)(qp_);
    qf1 = *(const bf16x8*)(qp_ + 32);
  }

  floatx4 ao[4], aol;
  #pragma unroll
  for (int t = 0; t < 4; t++) ao[t] = fz;
  aol = fz;
  float m_i[4];
  #pragma unroll
  for (int r = 0; r < 4; r++) m_i[r] = -3.0e38f;

  for (int it = 0; it < ntiles; it++) {
    int kv0 = it << 6;
    #pragma unroll
    for (int jj = 0; jj < 2; jj++) {
      int j = wave * 2 + jj;
      int r = j * 8 + r_in;
      int c = cpos ^ (r & 7);
      const unsigned short* gk =
          QKV + (rowbase + kv0 + r) * (long)QKV_LD + 1024 + hd0 + c * 8;
      async16(gk, Ks + j * 512);
      const unsigned short* gv =
          Vt + (long)(hd0 + r) * NROWS + rowbase + kv0 + c * 8;
      async16(gv, Vs + j * 512);
    }
    __syncthreads();

    floatx4 sacc[4];
    #pragma unroll
    for (int t = 0; t < 4; t++) {
      int row = t * 16 + l16;
      int sw = row & 7;
      bf16x8 kf0 = *(const bf16x8*)(Ks + row * 64 + (quad ^ sw) * 8);
      bf16x8 kf1 = *(const bf16x8*)(Ks + row * 64 + ((quad + 4) ^ sw) * 8);
      sacc[t] = __builtin_amdgcn_mfma_f32_16x16x32_bf16(qf0, kf0, fz, 0, 0, 0);
      sacc[t] = __builtin_amdgcn_mfma_f32_16x16x32_bf16(qf1, kf1, sacc[t], 0, 0, 0);
    }

    // causal mask on RAW scores (only the diagonal tile)
    if (it == ntiles - 1) {
      #pragma unroll
      for (int t = 0; t < 4; t++) {
        int kvc = kv0 + t * 16 + l16;
        #pragma unroll
        for (int r = 0; r < 4; r++)
          sacc[t][r] = (kvc > qrow + r) ? -1.0e30f : sacc[t][r];
      }
    }

    // max over raw scores (scale commutes with max: SCL > 0)
    float Mg = sacc[0][0];
    #pragma unroll
    for (int t = 0; t < 4; t++)
      #pragma unroll
      for (int r = 0; r < 4; r++) Mg = fmaxf(Mg, sacc[t][r]);
    Mg = fmaxf(Mg, ror16<1>(Mg));
    Mg = fmaxf(Mg, ror16<2>(Mg));
    Mg = fmaxf(Mg, ror16<4>(Mg));
    Mg = fmaxf(Mg, ror16<8>(Mg));
    float Mg_s = Mg * SCL;

    // defer-max: rescale only if the running max grew by > 8 (per-thread)
    float m_min = fminf(fminf(m_i[0], m_i[1]), fminf(m_i[2], m_i[3]));
    if (Mg_s > m_min + 8.0f) {
      #pragma unroll
      for (int r = 0; r < 4; r++) {
        float mn = fmaxf(m_i[r], Mg_s);
        float alpha = __builtin_amdgcn_exp2f(m_i[r] - mn);
        m_i[r] = mn;
        #pragma unroll
        for (int t = 0; t < 4; t++) ao[t][r] *= alpha;
        aol[r] *= alpha;
      }
    }

    #pragma unroll
    for (int t = 0; t < 4; t++)
      #pragma unroll
      for (int r = 0; r < 4; r++) {
        float p = __builtin_amdgcn_exp2f(fmaf(sacc[t][r], SCL, -m_i[r]));
        pw[(quad * 4 + r) * PLD + t * 16 + l16] =
            (unsigned short)(__float_as_uint(p) >> 16);
      }

    __asm__ volatile("s_waitcnt lgkmcnt(0)" ::: "memory");
    bf16x8 pf0 = *(const bf16x8*)(pw + l16 * PLD + quad * 8);
    bf16x8 pf1 = *(const bf16x8*)(pw + l16 * PLD + 32 + quad * 8);

    #pragma unroll
    for (int t = 0; t < 4; t++) {
      int row = t * 16 + l16;
      int sw = row & 7;
      bf16x8 vf0 = *(const bf16x8*)(Vs + row * 64 + (quad ^ sw) * 8);
      bf16x8 vf1 = *(const bf16x8*)(Vs + row * 64 + ((quad + 4) ^ sw) * 8);
      ao[t] = __builtin_amdgcn_mfma_f32_16x16x32_bf16(pf0, vf0, ao[t], 0, 0, 0);
      ao[t] = __builtin_amdgcn_mfma_f32_16x16x32_bf16(pf1, vf1, ao[t], 0, 0, 0);
    }
    aol = __builtin_amdgcn_mfma_f32_16x16x32_bf16(pf0, ones, aol, 0, 0, 0);
    aol = __builtin_amdgcn_mfma_f32_16x16x32_bf16(pf1, ones, aol, 0, 0, 0);

    __syncthreads();
  }

  float inv[4];
  #pragma unroll
  for (int r = 0; r < 4; r++) inv[r] = 1.0f / aol[r];
  #pragma unroll
  for (int t = 0; t < 4; t++)
    #pragma unroll
    for (int r = 0; r < 4; r++)
      Omat[(rowbase + qrow + r) * (long)D_MODEL + hd0 + t * 16 + l16] =
          f2bf(ao[t][r] * inv[r]);
}

// -------- fused residual add (x + partial) + layernorm --------
__global__ __launch_bounds__(256) void k_add_ln(
    const float* __restrict__ A, const float* __restrict__ P,
    const float* __restrict__ g, const float* __restrict__ be,
    float* __restrict__ Y, unsigned short* __restrict__ Ybf) {
  __shared__ float sb[4], ssb[4];
  int tid = threadIdx.x;
  long base = (long)blockIdx.x * D_MODEL + tid * 4;
  float4 a  = *(const float4*)(A + base);
  float4 p0 = *(const float4*)(P + base);
  float v0 = a.x + p0.x;
  float v1 = a.y + p0.y;
  float v2 = a.z + p0.z;
  float v3 = a.w + p0.w;
  float s  = v0 + v1 + v2 + v3;
  float ss = v0 * v0 + v1 * v1 + v2 * v2 + v3 * v3;
  #pragma unroll
  for (int o = 32; o >= 1; o >>= 1) {
    s  += __shfl_xor(s, o, 64);
    ss += __shfl_xor(ss, o, 64);
  }
  int wave = tid >> 6;
  if ((tid & 63) == 0) { sb[wave] = s; ssb[wave] = ss; }
  __syncthreads();
  s  = sb[0] + sb[1] + sb[2] + sb[3];
  ss = ssb[0] + ssb[1] + ssb[2] + ssb[3];
  float mu  = s * (1.0f / 1024.0f);
  float var = ss * (1.0f / 1024.0f) - mu * mu;
  float rstd = rsqrtf(var + 1e-6f);
  float4 gv  = *(const float4*)(g + tid * 4);
  float4 bev = *(const float4*)(be + tid * 4);
  float o0 = (v0 - mu) * rstd * gv.x + bev.x;
  float o1 = (v1 - mu) * rstd * gv.y + bev.y;
  float o2 = (v2 - mu) * rstd * gv.z + bev.z;
  float o3 = (v3 - mu) * rstd * gv.w + bev.w;
  if (Y) *(float4*)(Y + base) = make_float4(o0, o1, o2, o3);
  if (Ybf) {
    ushort4 u;
    u.x = f2bf(o0); u.y = f2bf(o1); u.z = f2bf(o2); u.w = f2bf(o3);
    *(ushort4*)(Ybf + base) = u;
  }
}

extern "C" void kernel_launch(void* const* d_in, const int* in_sizes, int n_in,
                              void* d_out, int out_size, void* d_ws, size_t ws_size,
                              hipStream_t stream) {
  (void)in_sizes; (void)n_in; (void)out_size; (void)ws_size;
  static bool s_attr = false;
  if (!s_attr) {
    hipFuncSetAttribute((const void*)k_gemm256,
                        hipFuncAttributeMaxDynamicSharedMemorySize, 131072);
    s_attr = true;
  }
  const float* x   = (const float*)d_in[0];
  const float* Wq  = (const float*)d_in[1];
  const float* bq  = (const float*)d_in[2];
  const float* Wk  = (const float*)d_in[3];
  const float* bk  = (const float*)d_in[4];
  const float* Wv  = (const float*)d_in[5];
  const float* bv  = (const float*)d_in[6];
  const float* Wo  = (const float*)d_in[7];
  const float* bo  = (const float*)d_in[8];
  const float* g1  = (const float*)d_in[9];
  const float* b1  = (const float*)d_in[10];
  const float* Wup = (const float*)d_in[11];
  const float* bup = (const float*)d_in[12];
  const float* Wdn = (const float*)d_in[13];
  const float* bdn = (const float*)d_in[14];
  const float* g2  = (const float*)d_in[15];
  const float* b2  = (const float*)d_in[16];
  float* out = (float*)d_out;

  char* ws = (char*)d_ws;
  size_t off = 0;
  auto alloc = [&](size_t bytes) {
    char* p = ws + off;
    off = (off + bytes + 255) & ~(size_t)255;
    return p;
  };
  unsigned short* x_bf   = (unsigned short*)alloc((size_t)NROWS * D_MODEL * 2);
  unsigned short* WqkvT  = (unsigned short*)alloc((size_t)QKV_LD * D_MODEL * 2);
  unsigned short* WoT    = (unsigned short*)alloc((size_t)D_MODEL * D_MODEL * 2);
  unsigned short* WupT   = (unsigned short*)alloc((size_t)D_FFN * D_MODEL * 2);
  unsigned short* WdnT   = (unsigned short*)alloc((size_t)D_MODEL * D_FFN * 2);
  float*          bqkv   = (float*)alloc((size_t)QKV_LD * 4);
  unsigned short* qkv_bf = (unsigned short*)alloc((size_t)NROWS * QKV_LD * 2);
  unsigned short* Vt     = (unsigned short*)alloc((size_t)D_MODEL * NROWS * 2);
  unsigned short* mid_bf = (unsigned short*)alloc((size_t)NROWS * D_MODEL * 2);
  float*          x1f    = (float*)alloc((size_t)NROWS * D_MODEL * 4);
  unsigned short* x1bf   = (unsigned short*)alloc((size_t)NROWS * D_MODEL * 2);
  float*          part   = (float*)alloc((size_t)NROWS * D_MODEL * 4);
  unsigned short* h_bf   = (unsigned short*)alloc((size_t)NROWS * D_FFN * 2);

  k_f32_to_bf16<<<4096, 256, 0, stream>>>(x, x_bf, (long)NROWS * D_MODEL);
  k_transpose_sq<<<dim3(32, 32, 4), 256, 0, stream>>>(Wq, Wk, Wv, Wo, WqkvT, WoT);
  k_transpose_bf16<<<dim3(128, 32), 256, 0, stream>>>(Wup, WupT, D_MODEL, D_FFN);
  k_transpose_bf16<<<dim3(32, 128), 256, 0, stream>>>(Wdn, WdnT, D_FFN, D_MODEL);
  k_pack_bias<<<12, 256, 0, stream>>>(bq, bk, bv, bqkv);

  // QKV: M=4096, N=3072, K=1024 -> 128^2 tiles, 768 blocks
  k_gemm128<<<dim3(32, 24), 512, 0, stream>>>(x_bf, WqkvT, bqkv, qkv_bf,
                                              NROWS, QKV_LD, D_MODEL, 0);
  k_transpose_v<<<dim3(64, 16), 256, 0, stream>>>(qkv_bf, Vt);

  // 1024 blocks: 32 q-tiles x 32 (b,h), heavy-first; whole grid co-resident
  k_attn<<<1024, 256, 0, stream>>>(qkv_bf, Vt, mid_bf);

  // Wo: M=4096, N=1024, K=1024 -> 256 blocks, no split-K, f32 out
  k_gemm128<<<dim3(32, 8), 512, 0, stream>>>(mid_bf, WoT, bo, part,
                                             NROWS, D_MODEL, D_MODEL, 1);
  k_add_ln<<<4096, 256, 0, stream>>>(x, part, g1, b1, x1f, x1bf);

  // Up: M=4096, N=4096, K=1024 -> 256^2 tiles fill exactly 256 blocks
  k_gemm256<<<dim3(16, 16, 1), 512, 131072, stream>>>(x1bf, WupT, bup, h_bf,
                                                      NROWS, D_FFN, D_MODEL, 2);
  // Down: M=4096, N=1024, K=4096 -> 256 blocks, no split-K, f32 out
  k_gemm128<<<dim3(32, 8), 512, 0, stream>>>(h_bf, WdnT, bdn, part,
                                             NROWS, D_MODEL, D_FFN, 1);
  k_add_ln<<<4096, 256, 0, stream>>>(x1f, part, g2, b2, out, nullptr);
}

// Round 4
// 346.584 us; speedup vs baseline: 1.0733x; 1.0733x over previous
//
#include <hip/hip_runtime.h>

#define D_MODEL 1024
#define D_FFN   4096
#define SEQ     2048
#define NROWS   4096   // B*S
#define QKV_LD  3072

typedef __bf16 bf16x8 __attribute__((ext_vector_type(8)));
typedef float  floatx4 __attribute__((ext_vector_type(4)));

#define MFMA_BF16 __builtin_amdgcn_mfma_f32_16x16x32_bf16

__device__ __forceinline__ unsigned short f2bf(float f) {
  unsigned int u = __float_as_uint(f);
  u += 0x7FFFu + ((u >> 16) & 1u);   // RNE
  return (unsigned short)(u >> 16);
}

// DPP row_ror<N> within 16-lane rows (VALU-speed cross-lane; no LDS pipe)
template <int C>
__device__ __forceinline__ float ror16(float x) {
  return __int_as_float(
      __builtin_amdgcn_mov_dpp(__float_as_int(x), 0x120 | C, 0xf, 0xf, true));
}

// async global->LDS, 16B per lane. LDS dest = wave-uniform base + lane*16.
__device__ __forceinline__ void async16(const unsigned short* g, unsigned short* l) {
  __builtin_amdgcn_global_load_lds(
      (const __attribute__((address_space(1))) unsigned int*)g,
      (__attribute__((address_space(3))) unsigned int*)l, 16, 0, 0);
}

// ---------------- fp32 -> bf16 elementwise ----------------
__global__ __launch_bounds__(256) void k_f32_to_bf16(
    const float* __restrict__ in, unsigned short* __restrict__ outp, long n) {
  long i = ((long)blockIdx.x * 256 + threadIdx.x) * 4;
  if (i >= n) return;
  float4 v = *(const float4*)(in + i);
  ushort4 o;
  o.x = f2bf(v.x); o.y = f2bf(v.y); o.z = f2bf(v.z); o.w = f2bf(v.w);
  *(ushort4*)(outp + i) = o;
}

// ------------- transpose+convert: W[R][C] f32 -> WT[C][R] bf16 -------------
__global__ __launch_bounds__(256) void k_transpose_bf16(
    const float* __restrict__ W, unsigned short* __restrict__ WT, int R, int C) {
  __shared__ float tile[32][33];
  int tx = threadIdx.x & 31, ty = threadIdx.x >> 5;
  long bx = (long)blockIdx.x * 32;
  long by = (long)blockIdx.y * 32;
  #pragma unroll
  for (int j = 0; j < 4; j++)
    tile[ty + j * 8][tx] = W[(by + ty + j * 8) * C + bx + tx];
  __syncthreads();
  #pragma unroll
  for (int j = 0; j < 4; j++)
    WT[(bx + ty + j * 8) * R + by + tx] = f2bf(tile[tx][ty + j * 8]);
}

// ------------- 1024x1024 weight transposes fused (z: Wq,Wk,Wv -> WqkvT; Wo -> WoT) ------
__global__ __launch_bounds__(256) void k_transpose_sq(
    const float* __restrict__ Wq, const float* __restrict__ Wk,
    const float* __restrict__ Wv, const float* __restrict__ Wo,
    unsigned short* __restrict__ WqkvT, unsigned short* __restrict__ WoT) {
  __shared__ float tile[32][33];
  int z = blockIdx.z;
  const float* W = (z == 0) ? Wq : (z == 1) ? Wk : (z == 2) ? Wv : Wo;
  unsigned short* dst = (z < 3) ? (WqkvT + (size_t)z * D_MODEL * D_MODEL) : WoT;
  int tx = threadIdx.x & 31, ty = threadIdx.x >> 5;
  long bx = (long)blockIdx.x * 32;
  long by = (long)blockIdx.y * 32;
  #pragma unroll
  for (int j = 0; j < 4; j++)
    tile[ty + j * 8][tx] = W[(by + ty + j * 8) * D_MODEL + bx + tx];
  __syncthreads();
  #pragma unroll
  for (int j = 0; j < 4; j++)
    dst[(bx + ty + j * 8) * D_MODEL + by + tx] = f2bf(tile[tx][ty + j * 8]);
}

__global__ __launch_bounds__(256) void k_pack_bias(
    const float* __restrict__ bq, const float* __restrict__ bk,
    const float* __restrict__ bv, float* __restrict__ dst) {
  int i = blockIdx.x * 256 + threadIdx.x;
  if (i >= 3072) return;
  float v = (i < 1024) ? bq[i] : (i < 2048) ? bk[i - 1024] : bv[i - 2048];
  dst[i] = v;
}

// ------------- V^T: QKV[:, 2048+d] -> Vt[d][row]  (bf16) -------------
__global__ __launch_bounds__(256) void k_transpose_v(
    const unsigned short* __restrict__ QKV, unsigned short* __restrict__ Vt) {
  __shared__ unsigned short tile[64][72];
  int r0 = blockIdx.x * 64;
  int c0 = blockIdx.y * 64;
  int tx = threadIdx.x & 15, ty = threadIdx.x >> 4;
  #pragma unroll
  for (int j = 0; j < 4; j++) {
    int r = ty + j * 16;
    *(ushort4*)&tile[r][tx * 4] =
        *(const ushort4*)(QKV + (long)(r0 + r) * QKV_LD + 2048 + c0 + tx * 4);
  }
  __syncthreads();
  #pragma unroll
  for (int j = 0; j < 4; j++) {
    int d = ty + j * 16;
    ushort4 o;
    o.x = tile[tx * 4 + 0][d];
    o.y = tile[tx * 4 + 1][d];
    o.z = tile[tx * 4 + 2][d];
    o.w = tile[tx * 4 + 3][d];
    *(ushort4*)(Vt + (long)(c0 + d) * NROWS + r0 + tx * 4) = o;
  }
}

// ============ 128x128 8-wave bf16 MFMA GEMM, 2 blocks/CU, counted vmcnt ============
// C[M][N] = A[M][K] @ Bt[N][K]^T + bias. BK=64, double-buffered 64 KiB static LDS.
// bf16 output path uses an LDS-staged coalesced epilogue (full 64B-line stores);
// f32 path (split-free partials) is already line-coalesced with scalar stores.
__global__ __launch_bounds__(512, 4) void k_gemm128(
    const unsigned short* __restrict__ A,
    const unsigned short* __restrict__ Bt,
    const float* __restrict__ bias,
    void* __restrict__ Cp, int M, int N, int K, int flags) {
  __shared__ unsigned short lds[2 * 16384];   // [2 buf][A 8192 | B 8192] u16 = 64 KiB
  int tid = threadIdx.x, lane = tid & 63, wave = tid >> 6;
  int quad = lane >> 4, l16 = lane & 15;
  int wm = wave >> 2, wn = wave & 3;          // 2M x 4N wave grid

  int gx = gridDim.x;
  int nwg = gx * gridDim.y;                   // % 8 == 0
  int orig = blockIdx.y * gx + blockIdx.x;
  int wg = (orig & 7) * (nwg >> 3) + (orig >> 3);
  long bm = (long)(wg % gx) * 128;
  long bn = (long)(wg / gx) * 128;

  int T = K / 64;

  const floatx4 fz = {0.f, 0.f, 0.f, 0.f};
  floatx4 acc[4][2];
  #pragma unroll
  for (int i = 0; i < 4; i++)
    #pragma unroll
    for (int j = 0; j < 2; j++) acc[i][j] = fz;

  int srow = tid >> 3;
  int sc = (tid & 7) ^ (srow & 7);
  const unsigned short* Ag = A + (bm + srow) * (long)K + sc * 8;
  const unsigned short* Bg = Bt + (bn + srow) * (long)K + sc * 8;

  auto stage = [&](int tt, int c) {
    unsigned short* An = lds + c * 16384;
    unsigned short* Bn = An + 8192;
    long ko = (long)tt * 64;
    async16(Ag + ko, An + wave * 512);
    async16(Ag + 64 * (long)K + ko, An + 4096 + wave * 512);
    async16(Bg + ko, Bn + wave * 512);
    async16(Bg + 64 * (long)K + ko, Bn + 4096 + wave * 512);
  };

  int aoff = (wm * 64 + l16) * 64;
  int boff = (wn * 32 + l16) * 64;
  int sw = l16 & 7;
  int ca0 = (quad ^ sw) * 8;          // k-chunks 0..3 (h=0)
  int ca1 = ((4 + quad) ^ sw) * 8;    // k-chunks 4..7 (h=1)

  stage(0, 0);
  for (int t = 0; t < T; t++) {
    int c = t & 1;
    const unsigned short* Ac = lds + c * 16384;
    const unsigned short* Bc = Ac + 8192;
    int tn = (t + 1 < T) ? t + 1 : T - 1;   // clamp keeps vmcnt count uniform
    stage(tn, c ^ 1);
    __asm__ volatile("s_waitcnt vmcnt(4)" ::: "memory");
    __builtin_amdgcn_s_barrier();

    bf16x8 af[4][2], bfr[2][2];
    #pragma unroll
    for (int m = 0; m < 4; m++) {
      af[m][0] = *(const bf16x8*)(Ac + aoff + m * 1024 + ca0);
      af[m][1] = *(const bf16x8*)(Ac + aoff + m * 1024 + ca1);
    }
    #pragma unroll
    for (int n = 0; n < 2; n++) {
      bfr[n][0] = *(const bf16x8*)(Bc + boff + n * 1024 + ca0);
      bfr[n][1] = *(const bf16x8*)(Bc + boff + n * 1024 + ca1);
    }
    __asm__ volatile("s_waitcnt lgkmcnt(0)" ::: "memory");
    __builtin_amdgcn_s_setprio(1);
    #pragma unroll
    for (int h = 0; h < 2; h++)
      #pragma unroll
      for (int m = 0; m < 4; m++)
        #pragma unroll
        for (int n = 0; n < 2; n++)
          acc[m][n] = MFMA_BF16(af[m][h], bfr[n][h], acc[m][n], 0, 0, 0);
    __builtin_amdgcn_s_setprio(0);
    __builtin_amdgcn_s_barrier();
  }

  bool f32out = (flags & 1) != 0;
  bool relu   = (flags & 2) != 0;
  if (f32out) {
    float* outf = (float*)Cp;
    #pragma unroll
    for (int n = 0; n < 2; n++) {
      long col = bn + wn * 32 + n * 16 + l16;
      float bvv = bias[col];
      #pragma unroll
      for (int m = 0; m < 4; m++) {
        long row = bm + wm * 64 + m * 16 + quad * 4;
        #pragma unroll
        for (int r = 0; r < 4; r++) {
          float v = acc[m][n][r] + bvv;
          if (relu) v = fmaxf(v, 0.0f);
          outf[(row + r) * (long)N + col] = v;
        }
      }
    }
  } else {
    // drain the clamp-stage's in-flight LDS writes before reusing LDS,
    // then barrier so no other wave's loads are still landing.
    __asm__ volatile("s_waitcnt vmcnt(0)" ::: "memory");
    __syncthreads();
    unsigned short* outh = (unsigned short*)Cp;
    // per-wave private 64x32 u16 tile, row stride 40 u16 (80B: 16B-aligned,
    // rows spread across banks; write conflicts <=4-way, reads conflict-free)
    unsigned short* lw = lds + wave * 2560;
    #pragma unroll
    for (int n = 0; n < 2; n++) {
      long col = bn + wn * 32 + n * 16 + l16;
      float bvv = bias[col];
      #pragma unroll
      for (int m = 0; m < 4; m++) {
        #pragma unroll
        for (int r = 0; r < 4; r++) {
          float v = acc[m][n][r] + bvv;
          if (relu) v = fmaxf(v, 0.0f);
          lw[(m * 16 + quad * 4 + r) * 40 + n * 16 + l16] = f2bf(v);
        }
      }
    }
    // read back row-major and store full 64B lines (b128 per lane)
    int rrb = lane >> 2;
    int c8 = (lane & 3) * 8;
    long grow = bm + wm * 64;
    long gcol = bn + wn * 32 + c8;
    #pragma unroll
    for (int k = 0; k < 4; k++) {
      int rr = rrb + k * 16;
      bf16x8 vv = *(const bf16x8*)(lw + rr * 40 + c8);
      *(bf16x8*)(outh + (grow + rr) * (long)N + gcol) = vv;
    }
  }
}

// ---------------- flash attention (causal), LDS-staged K/V ----------------
// One q-tile (64 rows) per block; 1024 blocks, heavy-first (qt descending).
#define PLD 72
__global__ __launch_bounds__(256) void k_attn(
    const unsigned short* __restrict__ QKV,
    const unsigned short* __restrict__ Vt,
    unsigned short* __restrict__ Omat) {
  __shared__ unsigned short Ks[64 * 64];   // [kv][d], chunk-swizzled
  __shared__ unsigned short Vs[64 * 64];   // [d][kv], chunk-swizzled
  __shared__ unsigned short Ps[4][16 * PLD];
  int tid = threadIdx.x;
  int lane = tid & 63, wave = tid >> 6;
  int quad = lane >> 4, l16 = lane & 15;
  int z = blockIdx.x;
  int bh = z & 31;
  int qt = 31 - (z >> 5);          // heavy blocks dispatch first
  int b = bh >> 4, h = bh & 15;
  long rowbase = (long)b * SEQ;
  int hd0 = h * 64;
  unsigned short* pw = &Ps[wave][0];
  const float SCL = 0.18033688f;   // 0.125 * log2(e)
  const floatx4 fz = {0.f, 0.f, 0.f, 0.f};

  int r_in = lane >> 3;
  int cpos = lane & 7;

  bf16x8 ones;
  #pragma unroll
  for (int i = 0; i < 8; i++) ones[i] = (__bf16)1.0f;

  int q0w = qt * 64 + wave * 16;
  int qrow = q0w + quad * 4;
  int ntiles = qt + 1;

  bf16x8 qf0, qf1;
  {
    const unsigned short* qp_ =
        QKV + (rowbase + q0w + l16) * (long)QKV_LD + hd0 + quad * 8;
    qf0 = *(const bf16x8*)(qp_);
    qf1 = *(const bf16x8*)(qp_ + 32);
  }

  floatx4 ao[4], aol;
  #pragma unroll
  for (int t = 0; t < 4; t++) ao[t] = fz;
  aol = fz;
  float m_i[4];
  #pragma unroll
  for (int r = 0; r < 4; r++) m_i[r] = -3.0e38f;

  for (int it = 0; it < ntiles; it++) {
    int kv0 = it << 6;
    #pragma unroll
    for (int jj = 0; jj < 2; jj++) {
      int j = wave * 2 + jj;
      int r = j * 8 + r_in;
      int c = cpos ^ (r & 7);
      const unsigned short* gk =
          QKV + (rowbase + kv0 + r) * (long)QKV_LD + 1024 + hd0 + c * 8;
      async16(gk, Ks + j * 512);
      const unsigned short* gv =
          Vt + (long)(hd0 + r) * NROWS + rowbase + kv0 + c * 8;
      async16(gv, Vs + j * 512);
    }
    __syncthreads();

    floatx4 sacc[4];
    #pragma unroll
    for (int t = 0; t < 4; t++) {
      int row = t * 16 + l16;
      int sw = row & 7;
      bf16x8 kf0 = *(const bf16x8*)(Ks + row * 64 + (quad ^ sw) * 8);
      bf16x8 kf1 = *(const bf16x8*)(Ks + row * 64 + ((quad + 4) ^ sw) * 8);
      sacc[t] = __builtin_amdgcn_mfma_f32_16x16x32_bf16(qf0, kf0, fz, 0, 0, 0);
      sacc[t] = __builtin_amdgcn_mfma_f32_16x16x32_bf16(qf1, kf1, sacc[t], 0, 0, 0);
    }

    // causal mask on RAW scores (only the diagonal tile)
    if (it == ntiles - 1) {
      #pragma unroll
      for (int t = 0; t < 4; t++) {
        int kvc = kv0 + t * 16 + l16;
        #pragma unroll
        for (int r = 0; r < 4; r++)
          sacc[t][r] = (kvc > qrow + r) ? -1.0e30f : sacc[t][r];
      }
    }

    // max over raw scores (scale commutes with max: SCL > 0)
    float Mg = sacc[0][0];
    #pragma unroll
    for (int t = 0; t < 4; t++)
      #pragma unroll
      for (int r = 0; r < 4; r++) Mg = fmaxf(Mg, sacc[t][r]);
    Mg = fmaxf(Mg, ror16<1>(Mg));
    Mg = fmaxf(Mg, ror16<2>(Mg));
    Mg = fmaxf(Mg, ror16<4>(Mg));
    Mg = fmaxf(Mg, ror16<8>(Mg));
    float Mg_s = Mg * SCL;

    // defer-max: rescale only if the running max grew by > 8
    float m_min = fminf(fminf(m_i[0], m_i[1]), fminf(m_i[2], m_i[3]));
    if (Mg_s > m_min + 8.0f) {
      #pragma unroll
      for (int r = 0; r < 4; r++) {
        float mn = fmaxf(m_i[r], Mg_s);
        float alpha = __builtin_amdgcn_exp2f(m_i[r] - mn);
        m_i[r] = mn;
        #pragma unroll
        for (int t = 0; t < 4; t++) ao[t][r] *= alpha;
        aol[r] *= alpha;
      }
    }

    #pragma unroll
    for (int t = 0; t < 4; t++)
      #pragma unroll
      for (int r = 0; r < 4; r++) {
        float p = __builtin_amdgcn_exp2f(fmaf(sacc[t][r], SCL, -m_i[r]));
        pw[(quad * 4 + r) * PLD + t * 16 + l16] =
            (unsigned short)(__float_as_uint(p) >> 16);
      }

    __asm__ volatile("s_waitcnt lgkmcnt(0)" ::: "memory");
    bf16x8 pf0 = *(const bf16x8*)(pw + l16 * PLD + quad * 8);
    bf16x8 pf1 = *(const bf16x8*)(pw + l16 * PLD + 32 + quad * 8);

    #pragma unroll
    for (int t = 0; t < 4; t++) {
      int row = t * 16 + l16;
      int sw = row & 7;
      bf16x8 vf0 = *(const bf16x8*)(Vs + row * 64 + (quad ^ sw) * 8);
      bf16x8 vf1 = *(const bf16x8*)(Vs + row * 64 + ((quad + 4) ^ sw) * 8);
      ao[t] = __builtin_amdgcn_mfma_f32_16x16x32_bf16(pf0, vf0, ao[t], 0, 0, 0);
      ao[t] = __builtin_amdgcn_mfma_f32_16x16x32_bf16(pf1, vf1, ao[t], 0, 0, 0);
    }
    aol = __builtin_amdgcn_mfma_f32_16x16x32_bf16(pf0, ones, aol, 0, 0, 0);
    aol = __builtin_amdgcn_mfma_f32_16x16x32_bf16(pf1, ones, aol, 0, 0, 0);

    __syncthreads();
  }

  float inv[4];
  #pragma unroll
  for (int r = 0; r < 4; r++) inv[r] = 1.0f / aol[r];
  #pragma unroll
  for (int t = 0; t < 4; t++)
    #pragma unroll
    for (int r = 0; r < 4; r++)
      Omat[(rowbase + qrow + r) * (long)D_MODEL + hd0 + t * 16 + l16] =
          f2bf(ao[t][r] * inv[r]);
}

// -------- fused residual add (x + partial) + layernorm --------
__global__ __launch_bounds__(256) void k_add_ln(
    const float* __restrict__ A, const float* __restrict__ P,
    const float* __restrict__ g, const float* __restrict__ be,
    float* __restrict__ Y, unsigned short* __restrict__ Ybf) {
  __shared__ float sb[4], ssb[4];
  int tid = threadIdx.x;
  long base = (long)blockIdx.x * D_MODEL + tid * 4;
  float4 a  = *(const float4*)(A + base);
  float4 p0 = *(const float4*)(P + base);
  float v0 = a.x + p0.x;
  float v1 = a.y + p0.y;
  float v2 = a.z + p0.z;
  float v3 = a.w + p0.w;
  float s  = v0 + v1 + v2 + v3;
  float ss = v0 * v0 + v1 * v1 + v2 * v2 + v3 * v3;
  #pragma unroll
  for (int o = 32; o >= 1; o >>= 1) {
    s  += __shfl_xor(s, o, 64);
    ss += __shfl_xor(ss, o, 64);
  }
  int wave = tid >> 6;
  if ((tid & 63) == 0) { sb[wave] = s; ssb[wave] = ss; }
  __syncthreads();
  s  = sb[0] + sb[1] + sb[2] + sb[3];
  ss = ssb[0] + ssb[1] + ssb[2] + ssb[3];
  float mu  = s * (1.0f / 1024.0f);
  float var = ss * (1.0f / 1024.0f) - mu * mu;
  float rstd = rsqrtf(var + 1e-6f);
  float4 gv  = *(const float4*)(g + tid * 4);
  float4 bev = *(const float4*)(be + tid * 4);
  float o0 = (v0 - mu) * rstd * gv.x + bev.x;
  float o1 = (v1 - mu) * rstd * gv.y + bev.y;
  float o2 = (v2 - mu) * rstd * gv.z + bev.z;
  float o3 = (v3 - mu) * rstd * gv.w + bev.w;
  if (Y) *(float4*)(Y + base) = make_float4(o0, o1, o2, o3);
  if (Ybf) {
    ushort4 u;
    u.x = f2bf(o0); u.y = f2bf(o1); u.z = f2bf(o2); u.w = f2bf(o3);
    *(ushort4*)(Ybf + base) = u;
  }
}

extern "C" void kernel_launch(void* const* d_in, const int* in_sizes, int n_in,
                              void* d_out, int out_size, void* d_ws, size_t ws_size,
                              hipStream_t stream) {
  (void)in_sizes; (void)n_in; (void)out_size; (void)ws_size;
  const float* x   = (const float*)d_in[0];
  const float* Wq  = (const float*)d_in[1];
  const float* bq  = (const float*)d_in[2];
  const float* Wk  = (const float*)d_in[3];
  const float* bk  = (const float*)d_in[4];
  const float* Wv  = (const float*)d_in[5];
  const float* bv  = (const float*)d_in[6];
  const float* Wo  = (const float*)d_in[7];
  const float* bo  = (const float*)d_in[8];
  const float* g1  = (const float*)d_in[9];
  const float* b1  = (const float*)d_in[10];
  const float* Wup = (const float*)d_in[11];
  const float* bup = (const float*)d_in[12];
  const float* Wdn = (const float*)d_in[13];
  const float* bdn = (const float*)d_in[14];
  const float* g2  = (const float*)d_in[15];
  const float* b2  = (const float*)d_in[16];
  float* out = (float*)d_out;

  char* ws = (char*)d_ws;
  size_t off = 0;
  auto alloc = [&](size_t bytes) {
    char* p = ws + off;
    off = (off + bytes + 255) & ~(size_t)255;
    return p;
  };
  unsigned short* x_bf   = (unsigned short*)alloc((size_t)NROWS * D_MODEL * 2);
  unsigned short* WqkvT  = (unsigned short*)alloc((size_t)QKV_LD * D_MODEL * 2);
  unsigned short* WoT    = (unsigned short*)alloc((size_t)D_MODEL * D_MODEL * 2);
  unsigned short* WupT   = (unsigned short*)alloc((size_t)D_FFN * D_MODEL * 2);
  unsigned short* WdnT   = (unsigned short*)alloc((size_t)D_MODEL * D_FFN * 2);
  float*          bqkv   = (float*)alloc((size_t)QKV_LD * 4);
  unsigned short* qkv_bf = (unsigned short*)alloc((size_t)NROWS * QKV_LD * 2);
  unsigned short* Vt     = (unsigned short*)alloc((size_t)D_MODEL * NROWS * 2);
  unsigned short* mid_bf = (unsigned short*)alloc((size_t)NROWS * D_MODEL * 2);
  float*          x1f    = (float*)alloc((size_t)NROWS * D_MODEL * 4);
  unsigned short* x1bf   = (unsigned short*)alloc((size_t)NROWS * D_MODEL * 2);
  float*          part   = (float*)alloc((size_t)NROWS * D_MODEL * 4);
  unsigned short* h_bf   = (unsigned short*)alloc((size_t)NROWS * D_FFN * 2);

  k_f32_to_bf16<<<4096, 256, 0, stream>>>(x, x_bf, (long)NROWS * D_MODEL);
  k_transpose_sq<<<dim3(32, 32, 4), 256, 0, stream>>>(Wq, Wk, Wv, Wo, WqkvT, WoT);
  k_transpose_bf16<<<dim3(128, 32), 256, 0, stream>>>(Wup, WupT, D_MODEL, D_FFN);
  k_transpose_bf16<<<dim3(32, 128), 256, 0, stream>>>(Wdn, WdnT, D_FFN, D_MODEL);
  k_pack_bias<<<12, 256, 0, stream>>>(bq, bk, bv, bqkv);

  // QKV: M=4096, N=3072, K=1024 -> 128^2 tiles, 768 blocks
  k_gemm128<<<dim3(32, 24), 512, 0, stream>>>(x_bf, WqkvT, bqkv, qkv_bf,
                                              NROWS, QKV_LD, D_MODEL, 0);
  k_transpose_v<<<dim3(64, 16), 256, 0, stream>>>(qkv_bf, Vt);

  // 1024 blocks: 32 q-tiles x 32 (b,h), heavy-first; whole grid co-resident
  k_attn<<<1024, 256, 0, stream>>>(qkv_bf, Vt, mid_bf);

  // Wo: M=4096, N=1024, K=1024 -> 256 blocks, f32 out
  k_gemm128<<<dim3(32, 8), 512, 0, stream>>>(mid_bf, WoT, bo, part,
                                             NROWS, D_MODEL, D_MODEL, 1);
  k_add_ln<<<4096, 256, 0, stream>>>(x, part, g1, b1, x1f, x1bf);

  // Up: M=4096, N=4096, K=1024 -> 128^2 tiles, 1024 blocks (2 resident/CU)
  k_gemm128<<<dim3(32, 32), 512, 0, stream>>>(x1bf, WupT, bup, h_bf,
                                              NROWS, D_FFN, D_MODEL, 2);
  // Down: M=4096, N=1024, K=4096 -> 256 blocks, f32 out
  k_gemm128<<<dim3(32, 8), 512, 0, stream>>>(h_bf, WdnT, bdn, part,
                                             NROWS, D_MODEL, D_FFN, 1);
  k_add_ln<<<4096, 256, 0, stream>>>(x1f, part, g2, b2, out, nullptr);
}

// Round 5
// 343.772 us; speedup vs baseline: 1.0820x; 1.0082x over previous
//
#include <hip/hip_runtime.h>

#define D_MODEL 1024
#define D_FFN   4096
#define SEQ     2048
#define NROWS   4096   // B*S
#define QKV_LD  3072

typedef __bf16 bf16x8 __attribute__((ext_vector_type(8)));
typedef float  floatx4 __attribute__((ext_vector_type(4)));

#define MFMA_BF16 __builtin_amdgcn_mfma_f32_16x16x32_bf16

__device__ __forceinline__ unsigned short f2bf(float f) {
  unsigned int u = __float_as_uint(f);
  u += 0x7FFFu + ((u >> 16) & 1u);   // RNE
  return (unsigned short)(u >> 16);
}

// DPP row_ror<N> within 16-lane rows (VALU-speed cross-lane; no LDS pipe)
template <int C>
__device__ __forceinline__ float ror16(float x) {
  return __int_as_float(
      __builtin_amdgcn_mov_dpp(__float_as_int(x), 0x120 | C, 0xf, 0xf, true));
}

// async global->LDS, 16B per lane. LDS dest = wave-uniform base + lane*16.
__device__ __forceinline__ void async16(const unsigned short* g, unsigned short* l) {
  __builtin_amdgcn_global_load_lds(
      (const __attribute__((address_space(1))) unsigned int*)g,
      (__attribute__((address_space(3))) unsigned int*)l, 16, 0, 0);
}

// ---------------- fp32 -> bf16 elementwise ----------------
__global__ __launch_bounds__(256) void k_f32_to_bf16(
    const float* __restrict__ in, unsigned short* __restrict__ outp, long n) {
  long i = ((long)blockIdx.x * 256 + threadIdx.x) * 4;
  if (i >= n) return;
  float4 v = *(const float4*)(in + i);
  ushort4 o;
  o.x = f2bf(v.x); o.y = f2bf(v.y); o.z = f2bf(v.z); o.w = f2bf(v.w);
  *(ushort4*)(outp + i) = o;
}

// ------------- transpose+convert: W[R][C] f32 -> WT[C][R] bf16 -------------
__global__ __launch_bounds__(256) void k_transpose_bf16(
    const float* __restrict__ W, unsigned short* __restrict__ WT, int R, int C) {
  __shared__ float tile[32][33];
  int tx = threadIdx.x & 31, ty = threadIdx.x >> 5;
  long bx = (long)blockIdx.x * 32;
  long by = (long)blockIdx.y * 32;
  #pragma unroll
  for (int j = 0; j < 4; j++)
    tile[ty + j * 8][tx] = W[(by + ty + j * 8) * C + bx + tx];
  __syncthreads();
  #pragma unroll
  for (int j = 0; j < 4; j++)
    WT[(bx + ty + j * 8) * R + by + tx] = f2bf(tile[tx][ty + j * 8]);
}

// ------------- 1024x1024 weight transposes fused (z: Wq,Wk,Wv -> WqkvT; Wo -> WoT) ------
__global__ __launch_bounds__(256) void k_transpose_sq(
    const float* __restrict__ Wq, const float* __restrict__ Wk,
    const float* __restrict__ Wv, const float* __restrict__ Wo,
    unsigned short* __restrict__ WqkvT, unsigned short* __restrict__ WoT) {
  __shared__ float tile[32][33];
  int z = blockIdx.z;
  const float* W = (z == 0) ? Wq : (z == 1) ? Wk : (z == 2) ? Wv : Wo;
  unsigned short* dst = (z < 3) ? (WqkvT + (size_t)z * D_MODEL * D_MODEL) : WoT;
  int tx = threadIdx.x & 31, ty = threadIdx.x >> 5;
  long bx = (long)blockIdx.x * 32;
  long by = (long)blockIdx.y * 32;
  #pragma unroll
  for (int j = 0; j < 4; j++)
    tile[ty + j * 8][tx] = W[(by + ty + j * 8) * D_MODEL + bx + tx];
  __syncthreads();
  #pragma unroll
  for (int j = 0; j < 4; j++)
    dst[(bx + ty + j * 8) * D_MODEL + by + tx] = f2bf(tile[tx][ty + j * 8]);
}

__global__ __launch_bounds__(256) void k_pack_bias(
    const float* __restrict__ bq, const float* __restrict__ bk,
    const float* __restrict__ bv, float* __restrict__ dst) {
  int i = blockIdx.x * 256 + threadIdx.x;
  if (i >= 3072) return;
  float v = (i < 1024) ? bq[i] : (i < 2048) ? bk[i - 1024] : bv[i - 2048];
  dst[i] = v;
}

// ------------- V^T: QKV[:, 2048+d] -> Vt[d][row]  (bf16) -------------
__global__ __launch_bounds__(256) void k_transpose_v(
    const unsigned short* __restrict__ QKV, unsigned short* __restrict__ Vt) {
  __shared__ unsigned short tile[64][72];
  int r0 = blockIdx.x * 64;
  int c0 = blockIdx.y * 64;
  int tx = threadIdx.x & 15, ty = threadIdx.x >> 4;
  #pragma unroll
  for (int j = 0; j < 4; j++) {
    int r = ty + j * 16;
    *(ushort4*)&tile[r][tx * 4] =
        *(const ushort4*)(QKV + (long)(r0 + r) * QKV_LD + 2048 + c0 + tx * 4);
  }
  __syncthreads();
  #pragma unroll
  for (int j = 0; j < 4; j++) {
    int d = ty + j * 16;
    ushort4 o;
    o.x = tile[tx * 4 + 0][d];
    o.y = tile[tx * 4 + 1][d];
    o.z = tile[tx * 4 + 2][d];
    o.w = tile[tx * 4 + 3][d];
    *(ushort4*)(Vt + (long)(c0 + d) * NROWS + r0 + tx * 4) = o;
  }
}

// ============ 128x128 8-wave bf16 MFMA GEMM, counted vmcnt, 2D XCD chunking ============
// C[M][N] = A[M][K] @ Bt[N][K]^T + bias. BK=64, double-buffered 64 KiB static LDS.
// XCD chunking: tile grid (nx x ny) split into rx x ry rects (rx*ry=8); XCD x owns
// rect (x/ry, x%ry) walked im-fast, so its 32 concurrent CUs cover an ~(nx/rx) x 4
// window -> per-XCD L2 sees few A/B panel streams instead of the whole A matrix.
// bf16 output path uses an LDS-staged coalesced epilogue (full 64B-line stores).
__global__ __launch_bounds__(512, 4) void k_gemm128(
    const unsigned short* __restrict__ A,
    const unsigned short* __restrict__ Bt,
    const float* __restrict__ bias,
    void* __restrict__ Cp, int M, int N, int K, int flags, int rx, int ry) {
  __shared__ unsigned short lds[2 * 16384];   // [2 buf][A 8192 | B 8192] u16 = 64 KiB
  int tid = threadIdx.x, lane = tid & 63, wave = tid >> 6;
  int quad = lane >> 4, l16 = lane & 15;
  int wm = wave >> 2, wn = wave & 3;          // 2M x 4N wave grid

  int nx = gridDim.x, ny = gridDim.y;
  int orig = blockIdx.y * nx + blockIdx.x;
  int xcd = orig & 7;                 // assumes round-robin dispatch->XCD (perf-only)
  int s = orig >> 3;                  // sequence within this XCD
  int mr = nx / rx, mc = ny / ry;     // tiles per rect
  int rr = xcd / ry, rc = xcd % ry;
  int im = s % mr, in_ = s / mr;      // im-fast: concurrent blocks share B-panels
  long bm = (long)(rr * mr + im) * 128;
  long bn = (long)(rc * mc + in_) * 128;

  int T = K / 64;

  const floatx4 fz = {0.f, 0.f, 0.f, 0.f};
  floatx4 acc[4][2];
  #pragma unroll
  for (int i = 0; i < 4; i++)
    #pragma unroll
    for (int j = 0; j < 2; j++) acc[i][j] = fz;

  int srow = tid >> 3;
  int sc = (tid & 7) ^ (srow & 7);
  const unsigned short* Ag = A + (bm + srow) * (long)K + sc * 8;
  const unsigned short* Bg = Bt + (bn + srow) * (long)K + sc * 8;

  auto stage = [&](int tt, int c) {
    unsigned short* An = lds + c * 16384;
    unsigned short* Bn = An + 8192;
    long ko = (long)tt * 64;
    async16(Ag + ko, An + wave * 512);
    async16(Ag + 64 * (long)K + ko, An + 4096 + wave * 512);
    async16(Bg + ko, Bn + wave * 512);
    async16(Bg + 64 * (long)K + ko, Bn + 4096 + wave * 512);
  };

  int aoff = (wm * 64 + l16) * 64;
  int boff = (wn * 32 + l16) * 64;
  int sw = l16 & 7;
  int ca0 = (quad ^ sw) * 8;          // k-chunks 0..3 (h=0)
  int ca1 = ((4 + quad) ^ sw) * 8;    // k-chunks 4..7 (h=1)

  stage(0, 0);
  for (int t = 0; t < T; t++) {
    int c = t & 1;
    const unsigned short* Ac = lds + c * 16384;
    const unsigned short* Bc = Ac + 8192;
    int tn = (t + 1 < T) ? t + 1 : T - 1;   // clamp keeps vmcnt count uniform
    stage(tn, c ^ 1);
    __asm__ volatile("s_waitcnt vmcnt(4)" ::: "memory");
    __builtin_amdgcn_s_barrier();

    bf16x8 af[4][2], bfr[2][2];
    #pragma unroll
    for (int m = 0; m < 4; m++) {
      af[m][0] = *(const bf16x8*)(Ac + aoff + m * 1024 + ca0);
      af[m][1] = *(const bf16x8*)(Ac + aoff + m * 1024 + ca1);
    }
    #pragma unroll
    for (int n = 0; n < 2; n++) {
      bfr[n][0] = *(const bf16x8*)(Bc + boff + n * 1024 + ca0);
      bfr[n][1] = *(const bf16x8*)(Bc + boff + n * 1024 + ca1);
    }
    __asm__ volatile("s_waitcnt lgkmcnt(0)" ::: "memory");
    __builtin_amdgcn_s_setprio(1);
    #pragma unroll
    for (int h = 0; h < 2; h++)
      #pragma unroll
      for (int m = 0; m < 4; m++)
        #pragma unroll
        for (int n = 0; n < 2; n++)
          acc[m][n] = MFMA_BF16(af[m][h], bfr[n][h], acc[m][n], 0, 0, 0);
    __builtin_amdgcn_s_setprio(0);
    __builtin_amdgcn_s_barrier();
  }

  bool f32out = (flags & 1) != 0;
  bool relu   = (flags & 2) != 0;
  if (f32out) {
    float* outf = (float*)Cp;
    #pragma unroll
    for (int n = 0; n < 2; n++) {
      long col = bn + wn * 32 + n * 16 + l16;
      float bvv = bias[col];
      #pragma unroll
      for (int m = 0; m < 4; m++) {
        long row = bm + wm * 64 + m * 16 + quad * 4;
        #pragma unroll
        for (int r = 0; r < 4; r++) {
          float v = acc[m][n][r] + bvv;
          if (relu) v = fmaxf(v, 0.0f);
          outf[(row + r) * (long)N + col] = v;
        }
      }
    }
  } else {
    // drain the clamp-stage's in-flight LDS writes before reusing LDS,
    // then barrier so no other wave's loads are still landing.
    __asm__ volatile("s_waitcnt vmcnt(0)" ::: "memory");
    __syncthreads();
    unsigned short* outh = (unsigned short*)Cp;
    // per-wave private 64x32 u16 tile, row stride 40 u16
    unsigned short* lw = lds + wave * 2560;
    #pragma unroll
    for (int n = 0; n < 2; n++) {
      long col = bn + wn * 32 + n * 16 + l16;
      float bvv = bias[col];
      #pragma unroll
      for (int m = 0; m < 4; m++) {
        #pragma unroll
        for (int r = 0; r < 4; r++) {
          float v = acc[m][n][r] + bvv;
          if (relu) v = fmaxf(v, 0.0f);
          lw[(m * 16 + quad * 4 + r) * 40 + n * 16 + l16] = f2bf(v);
        }
      }
    }
    // read back row-major and store full 64B lines (b128 per lane)
    int rrb = lane >> 2;
    int c8 = (lane & 3) * 8;
    long grow = bm + wm * 64;
    long gcol = bn + wn * 32 + c8;
    #pragma unroll
    for (int k = 0; k < 4; k++) {
      int rw = rrb + k * 16;
      bf16x8 vv = *(const bf16x8*)(lw + rw * 40 + c8);
      *(bf16x8*)(outh + (grow + rw) * (long)N + gcol) = vv;
    }
  }
}

// ---------------- flash attention (causal), LDS-staged K/V ----------------
// One q-tile (64 rows) per block; 1024 blocks, heavy-first (qt descending).
#define PLD 72
__global__ __launch_bounds__(256) void k_attn(
    const unsigned short* __restrict__ QKV,
    const unsigned short* __restrict__ Vt,
    unsigned short* __restrict__ Omat) {
  __shared__ unsigned short Ks[64 * 64];   // [kv][d], chunk-swizzled
  __shared__ unsigned short Vs[64 * 64];   // [d][kv], chunk-swizzled
  __shared__ unsigned short Ps[4][16 * PLD];
  int tid = threadIdx.x;
  int lane = tid & 63, wave = tid >> 6;
  int quad = lane >> 4, l16 = lane & 15;
  int z = blockIdx.x;
  int bh = z & 31;
  int qt = 31 - (z >> 5);          // heavy blocks dispatch first
  int b = bh >> 4, h = bh & 15;
  long rowbase = (long)b * SEQ;
  int hd0 = h * 64;
  unsigned short* pw = &Ps[wave][0];
  const float SCL = 0.18033688f;   // 0.125 * log2(e)
  const floatx4 fz = {0.f, 0.f, 0.f, 0.f};

  int r_in = lane >> 3;
  int cpos = lane & 7;

  bf16x8 ones;
  #pragma unroll
  for (int i = 0; i < 8; i++) ones[i] = (__bf16)1.0f;

  int q0w = qt * 64 + wave * 16;
  int qrow = q0w + quad * 4;
  int ntiles = qt + 1;

  bf16x8 qf0, qf1;
  {
    const unsigned short* qp_ =
        QKV + (rowbase + q0w + l16) * (long)QKV_LD + hd0 + quad * 8;
    qf0 = *(const bf16x8*)(qp_);
    qf1 = *(const bf16x8*)(qp_ + 32);
  }

  floatx4 ao[4], aol;
  #pragma unroll
  for (int t = 0; t < 4; t++) ao[t] = fz;
  aol = fz;
  float m_i[4];
  #pragma unroll
  for (int r = 0; r < 4; r++) m_i[r] = -3.0e38f;

  for (int it = 0; it < ntiles; it++) {
    int kv0 = it << 6;
    #pragma unroll
    for (int jj = 0; jj < 2; jj++) {
      int j = wave * 2 + jj;
      int r = j * 8 + r_in;
      int c = cpos ^ (r & 7);
      const unsigned short* gk =
          QKV + (rowbase + kv0 + r) * (long)QKV_LD + 1024 + hd0 + c * 8;
      async16(gk, Ks + j * 512);
      const unsigned short* gv =
          Vt + (long)(hd0 + r) * NROWS + rowbase + kv0 + c * 8;
      async16(gv, Vs + j * 512);
    }
    __syncthreads();

    floatx4 sacc[4];
    #pragma unroll
    for (int t = 0; t < 4; t++) {
      int row = t * 16 + l16;
      int sw = row & 7;
      bf16x8 kf0 = *(const bf16x8*)(Ks + row * 64 + (quad ^ sw) * 8);
      bf16x8 kf1 = *(const bf16x8*)(Ks + row * 64 + ((quad + 4) ^ sw) * 8);
      sacc[t] = __builtin_amdgcn_mfma_f32_16x16x32_bf16(qf0, kf0, fz, 0, 0, 0);
      sacc[t] = __builtin_amdgcn_mfma_f32_16x16x32_bf16(qf1, kf1, sacc[t], 0, 0, 0);
    }

    // causal mask on RAW scores (only the diagonal tile)
    if (it == ntiles - 1) {
      #pragma unroll
      for (int t = 0; t < 4; t++) {
        int kvc = kv0 + t * 16 + l16;
        #pragma unroll
        for (int r = 0; r < 4; r++)
          sacc[t][r] = (kvc > qrow + r) ? -1.0e30f : sacc[t][r];
      }
    }

    // max over raw scores (scale commutes with max: SCL > 0)
    float Mg = sacc[0][0];
    #pragma unroll
    for (int t = 0; t < 4; t++)
      #pragma unroll
      for (int r = 0; r < 4; r++) Mg = fmaxf(Mg, sacc[t][r]);
    Mg = fmaxf(Mg, ror16<1>(Mg));
    Mg = fmaxf(Mg, ror16<2>(Mg));
    Mg = fmaxf(Mg, ror16<4>(Mg));
    Mg = fmaxf(Mg, ror16<8>(Mg));
    float Mg_s = Mg * SCL;

    // defer-max: rescale only if the running max grew by > 8
    float m_min = fminf(fminf(m_i[0], m_i[1]), fminf(m_i[2], m_i[3]));
    if (Mg_s > m_min + 8.0f) {
      #pragma unroll
      for (int r = 0; r < 4; r++) {
        float mn = fmaxf(m_i[r], Mg_s);
        float alpha = __builtin_amdgcn_exp2f(m_i[r] - mn);
        m_i[r] = mn;
        #pragma unroll
        for (int t = 0; t < 4; t++) ao[t][r] *= alpha;
        aol[r] *= alpha;
      }
    }

    #pragma unroll
    for (int t = 0; t < 4; t++)
      #pragma unroll
      for (int r = 0; r < 4; r++) {
        float p = __builtin_amdgcn_exp2f(fmaf(sacc[t][r], SCL, -m_i[r]));
        pw[(quad * 4 + r) * PLD + t * 16 + l16] =
            (unsigned short)(__float_as_uint(p) >> 16);
      }

    __asm__ volatile("s_waitcnt lgkmcnt(0)" ::: "memory");
    bf16x8 pf0 = *(const bf16x8*)(pw + l16 * PLD + quad * 8);
    bf16x8 pf1 = *(const bf16x8*)(pw + l16 * PLD + 32 + quad * 8);

    #pragma unroll
    for (int t = 0; t < 4; t++) {
      int row = t * 16 + l16;
      int sw = row & 7;
      bf16x8 vf0 = *(const bf16x8*)(Vs + row * 64 + (quad ^ sw) * 8);
      bf16x8 vf1 = *(const bf16x8*)(Vs + row * 64 + ((quad + 4) ^ sw) * 8);
      ao[t] = __builtin_amdgcn_mfma_f32_16x16x32_bf16(pf0, vf0, ao[t], 0, 0, 0);
      ao[t] = __builtin_amdgcn_mfma_f32_16x16x32_bf16(pf1, vf1, ao[t], 0, 0, 0);
    }
    aol = __builtin_amdgcn_mfma_f32_16x16x32_bf16(pf0, ones, aol, 0, 0, 0);
    aol = __builtin_amdgcn_mfma_f32_16x16x32_bf16(pf1, ones, aol, 0, 0, 0);

    __syncthreads();
  }

  float inv[4];
  #pragma unroll
  for (int r = 0; r < 4; r++) inv[r] = 1.0f / aol[r];
  #pragma unroll
  for (int t = 0; t < 4; t++)
    #pragma unroll
    for (int r = 0; r < 4; r++)
      Omat[(rowbase + qrow + r) * (long)D_MODEL + hd0 + t * 16 + l16] =
          f2bf(ao[t][r] * inv[r]);
}

// -------- fused residual add (x + partial) + layernorm --------
__global__ __launch_bounds__(256) void k_add_ln(
    const float* __restrict__ A, const float* __restrict__ P,
    const float* __restrict__ g, const float* __restrict__ be,
    float* __restrict__ Y, unsigned short* __restrict__ Ybf) {
  __shared__ float sb[4], ssb[4];
  int tid = threadIdx.x;
  long base = (long)blockIdx.x * D_MODEL + tid * 4;
  float4 a  = *(const float4*)(A + base);
  float4 p0 = *(const float4*)(P + base);
  float v0 = a.x + p0.x;
  float v1 = a.y + p0.y;
  float v2 = a.z + p0.z;
  float v3 = a.w + p0.w;
  float s  = v0 + v1 + v2 + v3;
  float ss = v0 * v0 + v1 * v1 + v2 * v2 + v3 * v3;
  #pragma unroll
  for (int o = 32; o >= 1; o >>= 1) {
    s  += __shfl_xor(s, o, 64);
    ss += __shfl_xor(ss, o, 64);
  }
  int wave = tid >> 6;
  if ((tid & 63) == 0) { sb[wave] = s; ssb[wave] = ss; }
  __syncthreads();
  s  = sb[0] + sb[1] + sb[2] + sb[3];
  ss = ssb[0] + ssb[1] + ssb[2] + ssb[3];
  float mu  = s * (1.0f / 1024.0f);
  float var = ss * (1.0f / 1024.0f) - mu * mu;
  float rstd = rsqrtf(var + 1e-6f);
  float4 gv  = *(const float4*)(g + tid * 4);
  float4 bev = *(const float4*)(be + tid * 4);
  float o0 = (v0 - mu) * rstd * gv.x + bev.x;
  float o1 = (v1 - mu) * rstd * gv.y + bev.y;
  float o2 = (v2 - mu) * rstd * gv.z + bev.z;
  float o3 = (v3 - mu) * rstd * gv.w + bev.w;
  if (Y) *(float4*)(Y + base) = make_float4(o0, o1, o2, o3);
  if (Ybf) {
    ushort4 u;
    u.x = f2bf(o0); u.y = f2bf(o1); u.z = f2bf(o2); u.w = f2bf(o3);
    *(ushort4*)(Ybf + base) = u;
  }
}

extern "C" void kernel_launch(void* const* d_in, const int* in_sizes, int n_in,
                              void* d_out, int out_size, void* d_ws, size_t ws_size,
                              hipStream_t stream) {
  (void)in_sizes; (void)n_in; (void)out_size; (void)ws_size;
  const float* x   = (const float*)d_in[0];
  const float* Wq  = (const float*)d_in[1];
  const float* bq  = (const float*)d_in[2];
  const float* Wk  = (const float*)d_in[3];
  const float* bk  = (const float*)d_in[4];
  const float* Wv  = (const float*)d_in[5];
  const float* bv  = (const float*)d_in[6];
  const float* Wo  = (const float*)d_in[7];
  const float* bo  = (const float*)d_in[8];
  const float* g1  = (const float*)d_in[9];
  const float* b1  = (const float*)d_in[10];
  const float* Wup = (const float*)d_in[11];
  const float* bup = (const float*)d_in[12];
  const float* Wdn = (const float*)d_in[13];
  const float* bdn = (const float*)d_in[14];
  const float* g2  = (const float*)d_in[15];
  const float* b2  = (const float*)d_in[16];
  float* out = (float*)d_out;

  char* ws = (char*)d_ws;
  size_t off = 0;
  auto alloc = [&](size_t bytes) {
    char* p = ws + off;
    off = (off + bytes + 255) & ~(size_t)255;
    return p;
  };
  unsigned short* x_bf   = (unsigned short*)alloc((size_t)NROWS * D_MODEL * 2);
  unsigned short* WqkvT  = (unsigned short*)alloc((size_t)QKV_LD * D_MODEL * 2);
  unsigned short* WoT    = (unsigned short*)alloc((size_t)D_MODEL * D_MODEL * 2);
  unsigned short* WupT   = (unsigned short*)alloc((size_t)D_FFN * D_MODEL * 2);
  unsigned short* WdnT   = (unsigned short*)alloc((size_t)D_MODEL * D_FFN * 2);
  float*          bqkv   = (float*)alloc((size_t)QKV_LD * 4);
  unsigned short* qkv_bf = (unsigned short*)alloc((size_t)NROWS * QKV_LD * 2);
  unsigned short* Vt     = (unsigned short*)alloc((size_t)D_MODEL * NROWS * 2);
  unsigned short* mid_bf = (unsigned short*)alloc((size_t)NROWS * D_MODEL * 2);
  float*          x1f    = (float*)alloc((size_t)NROWS * D_MODEL * 4);
  unsigned short* x1bf   = (unsigned short*)alloc((size_t)NROWS * D_MODEL * 2);
  float*          part   = (float*)alloc((size_t)NROWS * D_MODEL * 4);
  unsigned short* h_bf   = (unsigned short*)alloc((size_t)NROWS * D_FFN * 2);

  k_f32_to_bf16<<<4096, 256, 0, stream>>>(x, x_bf, (long)NROWS * D_MODEL);
  k_transpose_sq<<<dim3(32, 32, 4), 256, 0, stream>>>(Wq, Wk, Wv, Wo, WqkvT, WoT);
  k_transpose_bf16<<<dim3(128, 32), 256, 0, stream>>>(Wup, WupT, D_MODEL, D_FFN);
  k_transpose_bf16<<<dim3(32, 128), 256, 0, stream>>>(Wdn, WdnT, D_FFN, D_MODEL);
  k_pack_bias<<<12, 256, 0, stream>>>(bq, bk, bv, bqkv);

  // QKV: M=4096, N=3072, K=1024 -> 768 blocks; XCD rect 8bm x 12bn
  k_gemm128<<<dim3(32, 24), 512, 0, stream>>>(x_bf, WqkvT, bqkv, qkv_bf,
                                              NROWS, QKV_LD, D_MODEL, 0, 4, 2);
  k_transpose_v<<<dim3(64, 16), 256, 0, stream>>>(qkv_bf, Vt);

  // 1024 blocks: 32 q-tiles x 32 (b,h), heavy-first; whole grid co-resident
  k_attn<<<1024, 256, 0, stream>>>(qkv_bf, Vt, mid_bf);

  // Wo: M=4096, N=1024, K=1024 -> 256 blocks; XCD rect 8bm x 4bn
  k_gemm128<<<dim3(32, 8), 512, 0, stream>>>(mid_bf, WoT, bo, part,
                                             NROWS, D_MODEL, D_MODEL, 1, 4, 2);
  k_add_ln<<<4096, 256, 0, stream>>>(x, part, g1, b1, x1f, x1bf);

  // Up: M=4096, N=4096, K=1024 -> 1024 blocks; XCD rect 8bm x 16bn
  k_gemm128<<<dim3(32, 32), 512, 0, stream>>>(x1bf, WupT, bup, h_bf,
                                              NROWS, D_FFN, D_MODEL, 2, 4, 2);
  // Down: M=4096, N=1024, K=4096 -> 256 blocks; XCD rect 8bm x 4bn
  k_gemm128<<<dim3(32, 8), 512, 0, stream>>>(h_bf, WdnT, bdn, part,
                                             NROWS, D_MODEL, D_FFN, 1, 4, 2);
  k_add_ln<<<4096, 256, 0, stream>>>(x1f, part, g2, b2, out, nullptr);
}